// Round 1
// baseline (704.118 us; speedup 1.0000x reference)
//
#include <hip/hip_runtime.h>
#include <math.h>

#define NB 8
#define SL 1024
#define DI 512
#define HH 8
#define KDN 64
#define VDN 64
#define ODN 512
#define ATT_SCALE 0.125f

// workspace layout (floats)
#define KT_OFF 0u          // [H][N][KD][S]  4,194,304
#define V_OFF  4194304u    // [H][N][S][VD]  4,194,304
#define G_OFF  8388608u    // [S][S]         1,048,576
#define Y_OFF  9437184u    // [N][S][H*VD]   4,194,304
// total 13,631,488 floats = 52 MB

#define ORD_NEG_INF 0x007FFFFFu

__device__ __forceinline__ unsigned fordu(float f) {
  unsigned b = __float_as_uint(f);
  return b ^ ((b & 0x80000000u) ? 0xFFFFFFFFu : 0x80000000u);
}
__device__ __forceinline__ float ifordu(unsigned k) {
  unsigned b = k ^ ((k & 0x80000000u) ? 0x80000000u : 0xFFFFFFFFu);
  return __uint_as_float(b);
}

// ---------------------------------------------------------------- kv proj ---
__global__ __launch_bounds__(256) void kvproj_kernel(
    const float* __restrict__ x, const float* __restrict__ Wk, const float* __restrict__ bk,
    const float* __restrict__ Wv, const float* __restrict__ bv, float* __restrict__ ws)
{
  __shared__ float xs[64][68];
  __shared__ float wks[64][68];
  __shared__ float wvs[64][68];
  const int tid = threadIdx.x;
  const int tx = tid & 15, ty = tid >> 4;
  const int m0 = blockIdx.x * 64;
  const int h = blockIdx.y;
  const float* wkb = Wk + (size_t)h * (DI * KDN);
  const float* wvb = Wv + (size_t)h * (DI * VDN);
  float ak[4][4] = {{0.f}};
  float av[4][4] = {{0.f}};
  for (int dt = 0; dt < DI / 64; ++dt) {
    __syncthreads();
#pragma unroll
    for (int it = 0; it < 4; ++it) {
      const int r = ty + it * 16;
      const int c = tx * 4;
      *(float4*)&xs[r][c]  = *(const float4*)&x[(size_t)(m0 + r) * DI + dt * 64 + c];
      *(float4*)&wks[r][c] = *(const float4*)&wkb[(size_t)(dt * 64 + r) * KDN + c];
      *(float4*)&wvs[r][c] = *(const float4*)&wvb[(size_t)(dt * 64 + r) * VDN + c];
    }
    __syncthreads();
#pragma unroll 4
    for (int dd = 0; dd < 64; ++dd) {
      float a[4];
#pragma unroll
      for (int i = 0; i < 4; ++i) a[i] = xs[ty * 4 + i][dd];
      const float4 bkv = *(const float4*)&wks[dd][tx * 4];
      const float4 bvv = *(const float4*)&wvs[dd][tx * 4];
      const float bkj[4] = {bkv.x, bkv.y, bkv.z, bkv.w};
      const float bvj[4] = {bvv.x, bvv.y, bvv.z, bvv.w};
#pragma unroll
      for (int i = 0; i < 4; ++i) {
#pragma unroll
        for (int j = 0; j < 4; ++j) {
          ak[i][j] = __fmaf_rn(a[i], bkj[j], ak[i][j]);
          av[i][j] = __fmaf_rn(a[i], bvj[j], av[i][j]);
        }
      }
    }
  }
  const int n = m0 >> 10;
  const int s0 = m0 & 1023;
  float* kT = ws + KT_OFF;
  float* vb = ws + V_OFF;
#pragma unroll
  for (int i = 0; i < 4; ++i) {
    const int s = s0 + ty * 4 + i;
    float4 vv;
    vv.x = av[i][0] + bv[h * VDN + tx * 4 + 0];
    vv.y = av[i][1] + bv[h * VDN + tx * 4 + 1];
    vv.z = av[i][2] + bv[h * VDN + tx * 4 + 2];
    vv.w = av[i][3] + bv[h * VDN + tx * 4 + 3];
    *(float4*)&vb[((size_t)(h * NB + n) * SL + s) * VDN + tx * 4] = vv;
#pragma unroll
    for (int j = 0; j < 4; ++j) {
      kT[((size_t)(h * NB + n) * KDN + tx * 4 + j) * SL + s] = ak[i][j] + bk[h * KDN + tx * 4 + j];
    }
  }
}

// ---------------------------------------------------------- graph softmax ---
__global__ __launch_bounds__(256) void gsoftmax_kernel(const float* __restrict__ gin, float* __restrict__ ws)
{
  float* gout = ws + G_OFF;
  const int row = blockIdx.x;
  const int tid = threadIdx.x;
  const int lane = tid & 63, wave = tid >> 6;
  __shared__ float red[4];
  __shared__ float red2[4];
  float v[4];
  float m = -INFINITY;
#pragma unroll
  for (int i = 0; i < 4; ++i) {
    v[i] = gin[(size_t)row * SL + tid + i * 256];
    m = fmaxf(m, v[i]);
  }
#pragma unroll
  for (int off = 32; off; off >>= 1) m = fmaxf(m, __shfl_xor(m, off));
  if (lane == 0) red[wave] = m;
  __syncthreads();
  m = fmaxf(fmaxf(red[0], red[1]), fmaxf(red[2], red[3]));
  float e[4];
  float s = 0.f;
#pragma unroll
  for (int i = 0; i < 4; ++i) { e[i] = __expf(v[i] - m); s += e[i]; }
#pragma unroll
  for (int off = 32; off; off >>= 1) s += __shfl_xor(s, off);
  if (lane == 0) red2[wave] = s;
  __syncthreads();
  s = red2[0] + red2[1] + red2[2] + red2[3];
  const float inv = 1.0f / s;
#pragma unroll
  for (int i = 0; i < 4; ++i) gout[(size_t)row * SL + tid + i * 256] = e[i] * inv;
}

// -------------------------------------------------------------- attention ---
// block: 256 thr (4 waves), 16 q-rows, one (h,n). Each wave owns 4 rows.
// att row kept in registers as order-preserving uint keys (2 per lane per 128-chunk).
__global__ __launch_bounds__(256) void attn_kernel(float* __restrict__ ws, const int* __restrict__ knn_p)
{
  __shared__ float ks[64][128];   // [kd][t-chunk]  32 KB (reused as compaction scratch later)
  __shared__ float kq[16][65];    // q-rows of k
  const int tid = threadIdx.x;
  const int lane = tid & 63;
  const int wave = tid >> 6;
  const int q0 = blockIdx.x * 16;
  const int hn = blockIdx.y;
  const int h = hn >> 3, n = hn & 7;
  const int K = knn_p[0];
  const float* kT = ws + KT_OFF + (size_t)hn * (KDN * SL);
  const float* vb = ws + V_OFF + (size_t)hn * (SL * VDN);
  float* y = ws + Y_OFF;

  for (int i = tid; i < 16 * 64; i += 256) {
    const int r = i & 15, kd = i >> 4;
    kq[r][kd] = kT[(size_t)kd * SL + q0 + r];
  }

  float ev[4][8][2];              // per-row keys (later e-values), static-indexed only
  const int cmax = (q0 + 15) >> 7;
  const int rbase = wave * 4;

#pragma unroll
  for (int c = 0; c < 8; ++c) {
    if (c <= cmax) {
      __syncthreads();
#pragma unroll
      for (int it = 0; it < 8; ++it) {
        const int i = tid * 4 + it * 1024;
        const int kd = i >> 7, t = i & 127;
        *(float4*)&ks[kd][t] = *(const float4*)&kT[(size_t)kd * SL + c * 128 + t];
      }
      __syncthreads();
      float ax[4] = {0.f, 0.f, 0.f, 0.f};
      float ay[4] = {0.f, 0.f, 0.f, 0.f};
#pragma unroll 8
      for (int kd = 0; kd < 64; ++kd) {
        const float2 kv = *(const float2*)&ks[kd][lane * 2];
#pragma unroll
        for (int rr = 0; rr < 4; ++rr) {
          const float kqv = kq[rbase + rr][kd];
          ax[rr] = __fmaf_rn(kqv, kv.x, ax[rr]);
          ay[rr] = __fmaf_rn(kqv, kv.y, ay[rr]);
        }
      }
      const int t0 = c * 128 + lane * 2;
#pragma unroll
      for (int rr = 0; rr < 4; ++rr) {
        const int q = q0 + rbase + rr;
        const unsigned k0 = (t0     <= q) ? fordu(ax[rr] * ATT_SCALE) : ORD_NEG_INF;
        const unsigned k1 = (t0 + 1 <= q) ? fordu(ay[rr] * ATT_SCALE) : ORD_NEG_INF;
        ev[rr][c][0] = __uint_as_float(k0);
        ev[rr][c][1] = __uint_as_float(k1);
      }
    } else {
#pragma unroll
      for (int rr = 0; rr < 4; ++rr) {
        ev[rr][c][0] = __uint_as_float(ORD_NEG_INF);
        ev[rr][c][1] = __uint_as_float(ORD_NEG_INF);
      }
    }
  }
  __syncthreads();  // all waves done reading ks -> reuse as per-wave scratch

  float* elist = ((float*)ks) + wave * 2048;              // 4 KB e-values
  unsigned short* tlist = (unsigned short*)(elist + 1024); // 2 KB t-indices

#pragma unroll
  for (int rr = 0; rr < 4; ++rr) {
    const int q = q0 + rbase + rr;
    const int cmr = q >> 7;

    // ---- row max (on keys; monotone) ----
    unsigned mk = 0u;
#pragma unroll
    for (int c = 0; c < 8; ++c) {
      if (c <= cmr) {
        const unsigned a = __float_as_uint(ev[rr][c][0]);
        const unsigned b = __float_as_uint(ev[rr][c][1]);
        mk = mk > a ? mk : a;
        mk = mk > b ? mk : b;
      }
    }
#pragma unroll
    for (int off = 32; off; off >>= 1) {
      const unsigned o = (unsigned)__shfl_xor((int)mk, off);
      mk = mk > o ? mk : o;
    }
    const float m = ifordu(mk);

    // ---- exact Kth-largest key via bitwise radix select (ballot counts) ----
    unsigned kthkey;
    if (q < K) {
      kthkey = ORD_NEG_INF;  // fewer than K valid entries -> kth is -inf -> keep all
    } else {
      unsigned prefix = 0u;
      int need = K;
      int cand = (cmr + 1) * 128;
      int b = 31;
      for (; b >= 0; --b) {
        const unsigned bitm = 1u << b;
        const unsigned himask = ~((bitm << 1) - 1u);
        int cnt = 0;
#pragma unroll
        for (int c = 0; c < 8; ++c) {
          if (c <= cmr) {
            const unsigned a = __float_as_uint(ev[rr][c][0]);
            const unsigned d = __float_as_uint(ev[rr][c][1]);
            cnt += (int)__popcll(__ballot(((a & himask) == prefix) && (a & bitm)));
            cnt += (int)__popcll(__ballot(((d & himask) == prefix) && (d & bitm)));
          }
        }
        if (cnt >= need) { prefix |= bitm; cand = cnt; }
        else             { need -= cnt;    cand -= cnt; }
        if (cand == need) break;   // remaining candidates all needed -> kth = min of them
      }
      if (b < 0) {
        kthkey = prefix;           // fully determined
      } else {
        const unsigned mm = ~((1u << b) - 1u);  // bits >= b
        unsigned mn = 0xFFFFFFFFu;
#pragma unroll
        for (int c = 0; c < 8; ++c) {
          if (c <= cmr) {
            const unsigned a = __float_as_uint(ev[rr][c][0]);
            const unsigned d = __float_as_uint(ev[rr][c][1]);
            if ((a & mm) == prefix && a < mn) mn = a;
            if ((d & mm) == prefix && d < mn) mn = d;
          }
        }
#pragma unroll
        for (int off = 32; off; off >>= 1) {
          const unsigned o = (unsigned)__shfl_xor((int)mn, off);
          mn = o < mn ? o : mn;
        }
        kthkey = mn;
      }
    }

    // ---- e = exp(att - m) for kept entries; Z ----
    float Z = 0.f;
#pragma unroll
    for (int c = 0; c < 8; ++c) {
#pragma unroll
      for (int j = 0; j < 2; ++j) {
        float e = 0.f;
        if (c <= cmr) {
          const unsigned k = __float_as_uint(ev[rr][c][j]);
          if (k >= kthkey) e = __expf(ifordu(k) - m);  // exp(-inf)=0 handles -inf kept ties
        }
        ev[rr][c][j] = e;
        Z += e;
      }
    }
#pragma unroll
    for (int off = 32; off; off >>= 1) Z += __shfl_xor(Z, off);

    // ---- compact kept (e>0) entries into per-wave LDS lists ----
    int cnt = 0;
#pragma unroll
    for (int c = 0; c < 8; ++c) {
      if (c <= cmr) {
#pragma unroll
        for (int j = 0; j < 2; ++j) {
          const float e = ev[rr][c][j];
          const unsigned long long msk = __ballot(e > 0.f);
          if (e > 0.f) {
            const int pos = cnt + (int)__popcll(msk & ((1ull << lane) - 1ull));
            elist[pos] = e;
            tlist[pos] = (unsigned short)(c * 128 + lane * 2 + j);
          }
          cnt += (int)__popcll(msk);
        }
      }
    }

    // ---- sparse PV: lane = vd ----
    float yacc = 0.f;
    int i2 = 0;
    for (; i2 + 4 <= cnt; i2 += 4) {
      const float e0 = elist[i2 + 0]; const int ta = tlist[i2 + 0];
      const float e1 = elist[i2 + 1]; const int tb = tlist[i2 + 1];
      const float e2 = elist[i2 + 2]; const int tc = tlist[i2 + 2];
      const float e3 = elist[i2 + 3]; const int td = tlist[i2 + 3];
      const float v0 = vb[(size_t)ta * VDN + lane];
      const float v1 = vb[(size_t)tb * VDN + lane];
      const float v2 = vb[(size_t)tc * VDN + lane];
      const float v3 = vb[(size_t)td * VDN + lane];
      yacc = __fmaf_rn(e0, v0, yacc);
      yacc = __fmaf_rn(e1, v1, yacc);
      yacc = __fmaf_rn(e2, v2, yacc);
      yacc = __fmaf_rn(e3, v3, yacc);
    }
    for (; i2 < cnt; ++i2) {
      yacc = __fmaf_rn(elist[i2], vb[(size_t)tlist[i2] * VDN + lane], yacc);
    }
    y[((size_t)(n * SL + q)) * ODN + h * VDN + lane] = yacc * (0.5f / Z);
  }
}

// ----------------------------------------------------- y += 0.5 * (g @ v) ---
__global__ __launch_bounds__(256) void gv_kernel(float* __restrict__ ws)
{
  __shared__ float as_[64][68];
  __shared__ float bs_[64][68];
  const int tid = threadIdx.x;
  const int tx = tid & 15, ty = tid >> 4;
  const int q0 = blockIdx.x * 64;
  const int hn = blockIdx.y;
  const int h = hn >> 3, n = hn & 7;
  const float* g = ws + G_OFF;
  const float* vb = ws + V_OFF + (size_t)hn * (SL * VDN);
  float* y = ws + Y_OFF;
  float acc[4][4] = {{0.f}};
  for (int kt = 0; kt < 16; ++kt) {
    __syncthreads();
#pragma unroll
    for (int it = 0; it < 4; ++it) {
      const int r = ty + it * 16;
      const int c = tx * 4;
      *(float4*)&as_[r][c] = *(const float4*)&g[(size_t)(q0 + r) * SL + kt * 64 + c];
      *(float4*)&bs_[r][c] = *(const float4*)&vb[(size_t)(kt * 64 + r) * VDN + c];
    }
    __syncthreads();
#pragma unroll 4
    for (int dd = 0; dd < 64; ++dd) {
      float a[4];
#pragma unroll
      for (int i = 0; i < 4; ++i) a[i] = as_[ty * 4 + i][dd];
      const float4 b4 = *(const float4*)&bs_[dd][tx * 4];
      const float bj[4] = {b4.x, b4.y, b4.z, b4.w};
#pragma unroll
      for (int i = 0; i < 4; ++i)
#pragma unroll
        for (int j = 0; j < 4; ++j)
          acc[i][j] = __fmaf_rn(a[i], bj[j], acc[i][j]);
    }
  }
#pragma unroll
  for (int i = 0; i < 4; ++i) {
    const size_t off = ((size_t)(n * SL + q0 + ty * 4 + i)) * ODN + h * VDN + tx * 4;
    float4 cur = *(float4*)&y[off];
    cur.x += 0.5f * acc[i][0];
    cur.y += 0.5f * acc[i][1];
    cur.z += 0.5f * acc[i][2];
    cur.w += 0.5f * acc[i][3];
    *(float4*)&y[off] = cur;
  }
}

// ------------------------------------------------- out = y @ Wout + bout ---
__global__ __launch_bounds__(256) void out_kernel(
    const float* __restrict__ Wout, const float* __restrict__ bout,
    const float* __restrict__ ws, float* __restrict__ out)
{
  __shared__ float as_[64][68];
  __shared__ float bs_[64][68];
  const int tid = threadIdx.x;
  const int tx = tid & 15, ty = tid >> 4;
  const int od0 = blockIdx.x * 64;
  const int m0 = blockIdx.y * 64;
  const float* y = ws + Y_OFF;
  float acc[4][4] = {{0.f}};
  for (int kt = 0; kt < 8; ++kt) {
    __syncthreads();
#pragma unroll
    for (int it = 0; it < 4; ++it) {
      const int r = ty + it * 16;
      const int c = tx * 4;
      *(float4*)&as_[r][c] = *(const float4*)&y[(size_t)(m0 + r) * ODN + kt * 64 + c];
      *(float4*)&bs_[r][c] = *(const float4*)&Wout[(size_t)(kt * 64 + r) * ODN + od0 + c];
    }
    __syncthreads();
#pragma unroll 4
    for (int dd = 0; dd < 64; ++dd) {
      float a[4];
#pragma unroll
      for (int i = 0; i < 4; ++i) a[i] = as_[ty * 4 + i][dd];
      const float4 b4 = *(const float4*)&bs_[dd][tx * 4];
      const float bj[4] = {b4.x, b4.y, b4.z, b4.w};
#pragma unroll
      for (int i = 0; i < 4; ++i)
#pragma unroll
        for (int j = 0; j < 4; ++j)
          acc[i][j] = __fmaf_rn(a[i], bj[j], acc[i][j]);
    }
  }
#pragma unroll
  for (int i = 0; i < 4; ++i) {
    float4 o4;
    o4.x = acc[i][0] + bout[od0 + tx * 4 + 0];
    o4.y = acc[i][1] + bout[od0 + tx * 4 + 1];
    o4.z = acc[i][2] + bout[od0 + tx * 4 + 2];
    o4.w = acc[i][3] + bout[od0 + tx * 4 + 3];
    *(float4*)&out[(size_t)(m0 + ty * 4 + i) * ODN + od0 + tx * 4] = o4;
  }
}

extern "C" void kernel_launch(void* const* d_in, const int* in_sizes, int n_in,
                              void* d_out, int out_size, void* d_ws, size_t ws_size,
                              hipStream_t stream)
{
  const float* x     = (const float*)d_in[0];
  const float* Wk    = (const float*)d_in[1];
  const float* bk    = (const float*)d_in[2];
  const float* Wv    = (const float*)d_in[3];
  const float* bv    = (const float*)d_in[4];
  const float* Wout  = (const float*)d_in[5];
  const float* bout  = (const float*)d_in[6];
  const float* graph = (const float*)d_in[7];
  const int*   knn   = (const int*)d_in[8];
  float* out = (float*)d_out;
  float* ws  = (float*)d_ws;

  kvproj_kernel<<<dim3(128, 8), 256, 0, stream>>>(x, Wk, bk, Wv, bv, ws);
  gsoftmax_kernel<<<dim3(1024), 256, 0, stream>>>(graph, ws);
  attn_kernel<<<dim3(64, 64), 256, 0, stream>>>(ws, knn);
  gv_kernel<<<dim3(16, 64), 256, 0, stream>>>(ws);
  out_kernel<<<dim3(8, 128), 256, 0, stream>>>(Wout, bout, ws, out);
}

// Round 2
// 616.913 us; speedup vs baseline: 1.1414x; 1.1414x over previous
//
#include <hip/hip_runtime.h>
#include <math.h>

#define NB 8
#define SL 1024
#define DI 512
#define HH 8
#define KDN 64
#define VDN 64
#define ODN 512
#define ATT_SCALE 0.125f

// workspace layout (float units unless noted)
// K_bf (bf16): [H*N][S][KD] at ushort offset 0  -> 4,194,304 ushorts (8 MB = 2,097,152 floats)
#define V_OFF  2097152u    // [H*N][S][VD] f32   16 MB
#define G_OFF  6291456u    // [S][S] f32          4 MB
#define Y_OFF  7340032u    // [N][S][H*VD] f32   16 MB
// total 11,534,336 floats = 44 MB

#define ORD_NEG_INF 0x007FFFFFu

typedef __attribute__((ext_vector_type(8))) short bf16x8;
typedef __attribute__((ext_vector_type(4))) float f32x4;

__device__ __forceinline__ unsigned fordu(float f) {
  unsigned b = __float_as_uint(f);
  return b ^ ((b & 0x80000000u) ? 0xFFFFFFFFu : 0x80000000u);
}
__device__ __forceinline__ float ifordu(unsigned k) {
  unsigned b = k ^ ((k & 0x80000000u) ? 0x80000000u : 0xFFFFFFFFu);
  return __uint_as_float(b);
}
__device__ __forceinline__ unsigned short f2bf(float f) {  // RNE f32->bf16
  unsigned u = __float_as_uint(f);
  unsigned r = (u + 0x7FFFu + ((u >> 16) & 1u)) >> 16;
  return (unsigned short)r;
}

// ---------------------------------------------------------------- kv proj ---
__global__ __launch_bounds__(256) void kvproj_kernel(
    const float* __restrict__ x, const float* __restrict__ Wk, const float* __restrict__ bk,
    const float* __restrict__ Wv, const float* __restrict__ bv, float* __restrict__ ws)
{
  __shared__ float xs[64][68];
  __shared__ float wks[64][68];
  __shared__ float wvs[64][68];
  const int tid = threadIdx.x;
  const int tx = tid & 15, ty = tid >> 4;
  const int m0 = blockIdx.x * 64;
  const int h = blockIdx.y;
  const float* wkb = Wk + (size_t)h * (DI * KDN);
  const float* wvb = Wv + (size_t)h * (DI * VDN);
  float ak[4][4] = {{0.f}};
  float av[4][4] = {{0.f}};
  for (int dt = 0; dt < DI / 64; ++dt) {
    __syncthreads();
#pragma unroll
    for (int it = 0; it < 4; ++it) {
      const int r = ty + it * 16;
      const int c = tx * 4;
      *(float4*)&xs[r][c]  = *(const float4*)&x[(size_t)(m0 + r) * DI + dt * 64 + c];
      *(float4*)&wks[r][c] = *(const float4*)&wkb[(size_t)(dt * 64 + r) * KDN + c];
      *(float4*)&wvs[r][c] = *(const float4*)&wvb[(size_t)(dt * 64 + r) * VDN + c];
    }
    __syncthreads();
#pragma unroll 4
    for (int dd = 0; dd < 64; ++dd) {
      float a[4];
#pragma unroll
      for (int i = 0; i < 4; ++i) a[i] = xs[ty * 4 + i][dd];
      const float4 bkv = *(const float4*)&wks[dd][tx * 4];
      const float4 bvv = *(const float4*)&wvs[dd][tx * 4];
      const float bkj[4] = {bkv.x, bkv.y, bkv.z, bkv.w};
      const float bvj[4] = {bvv.x, bvv.y, bvv.z, bvv.w};
#pragma unroll
      for (int i = 0; i < 4; ++i) {
#pragma unroll
        for (int j = 0; j < 4; ++j) {
          ak[i][j] = __fmaf_rn(a[i], bkj[j], ak[i][j]);
          av[i][j] = __fmaf_rn(a[i], bvj[j], av[i][j]);
        }
      }
    }
  }
  const int n = m0 >> 10;
  const int s0 = m0 & 1023;
  float* vb = ws + V_OFF;
  unsigned short* kbf = (unsigned short*)ws;
#pragma unroll
  for (int i = 0; i < 4; ++i) {
    const int s = s0 + ty * 4 + i;
    float4 vv;
    vv.x = av[i][0] + bv[h * VDN + tx * 4 + 0];
    vv.y = av[i][1] + bv[h * VDN + tx * 4 + 1];
    vv.z = av[i][2] + bv[h * VDN + tx * 4 + 2];
    vv.w = av[i][3] + bv[h * VDN + tx * 4 + 3];
    *(float4*)&vb[((size_t)(h * NB + n) * SL + s) * VDN + tx * 4] = vv;
    union { unsigned short u[4]; uint2 v2; } pk;
#pragma unroll
    for (int j = 0; j < 4; ++j) pk.u[j] = f2bf(ak[i][j] + bk[h * KDN + tx * 4 + j]);
    *(uint2*)&kbf[((size_t)(h * NB + n) * SL + s) * KDN + tx * 4] = pk.v2;
  }
}

// ---------------------------------------------------------- graph softmax ---
__global__ __launch_bounds__(256) void gsoftmax_kernel(const float* __restrict__ gin, float* __restrict__ ws)
{
  float* gout = ws + G_OFF;
  const int row = blockIdx.x;
  const int tid = threadIdx.x;
  const int lane = tid & 63, wave = tid >> 6;
  __shared__ float red[4];
  __shared__ float red2[4];
  float v[4];
  float m = -INFINITY;
#pragma unroll
  for (int i = 0; i < 4; ++i) {
    v[i] = gin[(size_t)row * SL + tid + i * 256];
    m = fmaxf(m, v[i]);
  }
#pragma unroll
  for (int off = 32; off; off >>= 1) m = fmaxf(m, __shfl_xor(m, off));
  if (lane == 0) red[wave] = m;
  __syncthreads();
  m = fmaxf(fmaxf(red[0], red[1]), fmaxf(red[2], red[3]));
  float e[4];
  float s = 0.f;
#pragma unroll
  for (int i = 0; i < 4; ++i) { e[i] = __expf(v[i] - m); s += e[i]; }
#pragma unroll
  for (int off = 32; off; off >>= 1) s += __shfl_xor(s, off);
  if (lane == 0) red2[wave] = s;
  __syncthreads();
  s = red2[0] + red2[1] + red2[2] + red2[3];
  const float inv = 1.0f / s;
#pragma unroll
  for (int i = 0; i < 4; ++i) gout[(size_t)row * SL + tid + i * 256] = e[i] * inv;
}

// -------------------------------------------------------------- attention ---
// block: 256 thr (4 waves), 16 q-rows, one (h,n).
// QK^T via bf16 MFMA -> padded LDS score strip (2 phases of 512 t) -> per-wave
// register row layout -> exact radix-select top-K -> softmax -> sparse PV.
__global__ __launch_bounds__(256) void attn_kernel(float* __restrict__ ws, const int* __restrict__ knn_p)
{
  __shared__ float S[16][516];    // 33 KB; reused as per-wave compaction lists later
  const int tid = threadIdx.x;
  const int lane = tid & 63;
  const int wave = tid >> 6;
  const int q0 = blockIdx.x * 16;
  const int hn = blockIdx.y;
  const int h = hn >> 3, n = hn & 7;
  const int K = knn_p[0];
  const unsigned short* kb = (const unsigned short*)ws + (size_t)hn * SL * KDN;
  const float* vb = ws + V_OFF + (size_t)hn * (SL * VDN);
  float* y = ws + Y_OFF;

  const int col = lane & 15, grp = lane >> 4;
  // A fragments (16 q-rows x K=64, two K32 steps), straight from global bf16 K
  const bf16x8 a0 = *(const bf16x8*)&kb[(size_t)(q0 + col) * KDN + grp * 8];
  const bf16x8 a1 = *(const bf16x8*)&kb[(size_t)(q0 + col) * KDN + 32 + grp * 8];

  const int T = q0 / 16 + 1;      // causal t-tiles needed
  const int rbase = wave * 4;

  float ev[4][8][2];              // per-row keys (later e-values), static-indexed only
#pragma unroll
  for (int rr = 0; rr < 4; ++rr)
#pragma unroll
    for (int c = 0; c < 8; ++c) {
      ev[rr][c][0] = __uint_as_float(ORD_NEG_INF);
      ev[rr][c][1] = __uint_as_float(ORD_NEG_INF);
    }

#pragma unroll
  for (int ph = 0; ph < 2; ++ph) {
    const int tlo = ph * 32;
    const int thi = (T < tlo + 32) ? T : (tlo + 32);
    if (thi > tlo) {            // block-uniform
      __syncthreads();
      for (int ti = tlo + wave; ti < thi; ti += 4) {
        const int t0 = ti * 16;
        const bf16x8 b0 = *(const bf16x8*)&kb[(size_t)(t0 + col) * KDN + grp * 8];
        const bf16x8 b1 = *(const bf16x8*)&kb[(size_t)(t0 + col) * KDN + 32 + grp * 8];
        f32x4 d = {0.f, 0.f, 0.f, 0.f};
        d = __builtin_amdgcn_mfma_f32_16x16x32_bf16(a0, b0, d, 0, 0, 0);
        d = __builtin_amdgcn_mfma_f32_16x16x32_bf16(a1, b1, d, 0, 0, 0);
        const int tl = t0 - ph * 512 + col;
#pragma unroll
        for (int r = 0; r < 4; ++r) S[grp * 4 + r][tl] = d[r];
      }
      __syncthreads();
      // pull this wave's 4 rows into the register row layout
#pragma unroll
      for (int rr = 0; rr < 4; ++rr) {
        const int q = q0 + rbase + rr;
        const int cmr = q >> 7;
#pragma unroll
        for (int cc = 0; cc < 4; ++cc) {
          const int c = ph * 4 + cc;
          if (c <= cmr) {
            const float2 sv = *(const float2*)&S[rbase + rr][cc * 128 + lane * 2];
            const int t0 = c * 128 + lane * 2;
            const unsigned k0 = (t0     <= q) ? fordu(sv.x * ATT_SCALE) : ORD_NEG_INF;
            const unsigned k1 = (t0 + 1 <= q) ? fordu(sv.y * ATT_SCALE) : ORD_NEG_INF;
            ev[rr][c][0] = __uint_as_float(k0);
            ev[rr][c][1] = __uint_as_float(k1);
          }
        }
      }
    }
  }
  __syncthreads();  // all rows read -> reuse S as per-wave scratch

  float* elist = &S[0][0] + wave * 1536;                   // 1024 e-values
  unsigned short* tlist = (unsigned short*)(elist + 1024); // 1024 t-indices

#pragma unroll
  for (int rr = 0; rr < 4; ++rr) {
    const int q = q0 + rbase + rr;
    const int cmr = q >> 7;

    // ---- row max (on keys; monotone) ----
    unsigned mk = 0u;
#pragma unroll
    for (int c = 0; c < 8; ++c) {
      if (c <= cmr) {
        const unsigned a = __float_as_uint(ev[rr][c][0]);
        const unsigned b = __float_as_uint(ev[rr][c][1]);
        mk = mk > a ? mk : a;
        mk = mk > b ? mk : b;
      }
    }
#pragma unroll
    for (int off = 32; off; off >>= 1) {
      const unsigned o = (unsigned)__shfl_xor((int)mk, off);
      mk = mk > o ? mk : o;
    }
    const float m = ifordu(mk);

    // ---- exact Kth-largest key via bitwise radix select (ballot counts) ----
    unsigned kthkey;
    if (q < K) {
      kthkey = ORD_NEG_INF;  // fewer than K valid entries -> keep all
    } else {
      unsigned prefix = 0u;
      int need = K;
      int cand = (cmr + 1) * 128;
      int b = 31;
      for (; b >= 0; --b) {
        const unsigned bitm = 1u << b;
        const unsigned himask = ~((bitm << 1) - 1u);
        int cnt = 0;
#pragma unroll
        for (int c = 0; c < 8; ++c) {
          if (c <= cmr) {
            const unsigned a = __float_as_uint(ev[rr][c][0]);
            const unsigned d = __float_as_uint(ev[rr][c][1]);
            cnt += (int)__popcll(__ballot(((a & himask) == prefix) && (a & bitm)));
            cnt += (int)__popcll(__ballot(((d & himask) == prefix) && (d & bitm)));
          }
        }
        if (cnt >= need) { prefix |= bitm; cand = cnt; }
        else             { need -= cnt;    cand -= cnt; }
        if (cand == need) break;   // remaining candidates all needed -> kth = min of them
      }
      if (b < 0) {
        kthkey = prefix;
      } else {
        const unsigned mm = ~((1u << b) - 1u);
        unsigned mn = 0xFFFFFFFFu;
#pragma unroll
        for (int c = 0; c < 8; ++c) {
          if (c <= cmr) {
            const unsigned a = __float_as_uint(ev[rr][c][0]);
            const unsigned d = __float_as_uint(ev[rr][c][1]);
            if ((a & mm) == prefix && a < mn) mn = a;
            if ((d & mm) == prefix && d < mn) mn = d;
          }
        }
#pragma unroll
        for (int off = 32; off; off >>= 1) {
          const unsigned o = (unsigned)__shfl_xor((int)mn, off);
          mn = o < mn ? o : mn;
        }
        kthkey = mn;
      }
    }

    // ---- e = exp(att - m) for kept entries; Z ----
    float Z = 0.f;
#pragma unroll
    for (int c = 0; c < 8; ++c) {
#pragma unroll
      for (int j = 0; j < 2; ++j) {
        float e = 0.f;
        if (c <= cmr) {
          const unsigned k = __float_as_uint(ev[rr][c][j]);
          if (k >= kthkey) e = __expf(ifordu(k) - m);  // exp(-inf)=0 for kept -inf ties
        }
        ev[rr][c][j] = e;
        Z += e;
      }
    }
#pragma unroll
    for (int off = 32; off; off >>= 1) Z += __shfl_xor(Z, off);

    // ---- compact kept (e>0) entries into per-wave LDS lists ----
    int cnt = 0;
#pragma unroll
    for (int c = 0; c < 8; ++c) {
      if (c <= cmr) {
#pragma unroll
        for (int j = 0; j < 2; ++j) {
          const float e = ev[rr][c][j];
          const unsigned long long msk = __ballot(e > 0.f);
          if (e > 0.f) {
            const int pos = cnt + (int)__popcll(msk & ((1ull << lane) - 1ull));
            elist[pos] = e;
            tlist[pos] = (unsigned short)(c * 128 + lane * 2 + j);
          }
          cnt += (int)__popcll(msk);
        }
      }
    }

    // ---- sparse PV: lane = vd ----
    float yacc = 0.f;
    int i2 = 0;
    for (; i2 + 4 <= cnt; i2 += 4) {
      const float e0 = elist[i2 + 0]; const int ta = tlist[i2 + 0];
      const float e1 = elist[i2 + 1]; const int tb = tlist[i2 + 1];
      const float e2 = elist[i2 + 2]; const int tc = tlist[i2 + 2];
      const float e3 = elist[i2 + 3]; const int td = tlist[i2 + 3];
      const float v0 = vb[(size_t)ta * VDN + lane];
      const float v1 = vb[(size_t)tb * VDN + lane];
      const float v2 = vb[(size_t)tc * VDN + lane];
      const float v3 = vb[(size_t)td * VDN + lane];
      yacc = __fmaf_rn(e0, v0, yacc);
      yacc = __fmaf_rn(e1, v1, yacc);
      yacc = __fmaf_rn(e2, v2, yacc);
      yacc = __fmaf_rn(e3, v3, yacc);
    }
    for (; i2 < cnt; ++i2) {
      yacc = __fmaf_rn(elist[i2], vb[(size_t)tlist[i2] * VDN + lane], yacc);
    }
    y[((size_t)(n * SL + q)) * ODN + h * VDN + lane] = yacc * (0.5f / Z);
  }
}

// ----------------------------------------------------- y += 0.5 * (g @ v) ---
__global__ __launch_bounds__(256) void gv_kernel(float* __restrict__ ws)
{
  __shared__ float as_[64][68];
  __shared__ float bs_[64][68];
  const int tid = threadIdx.x;
  const int tx = tid & 15, ty = tid >> 4;
  const int q0 = blockIdx.x * 64;
  const int hn = blockIdx.y;
  const int h = hn >> 3, n = hn & 7;
  const float* g = ws + G_OFF;
  const float* vb = ws + V_OFF + (size_t)hn * (SL * VDN);
  float* y = ws + Y_OFF;
  float acc[4][4] = {{0.f}};
  for (int kt = 0; kt < 16; ++kt) {
    __syncthreads();
#pragma unroll
    for (int it = 0; it < 4; ++it) {
      const int r = ty + it * 16;
      const int c = tx * 4;
      *(float4*)&as_[r][c] = *(const float4*)&g[(size_t)(q0 + r) * SL + kt * 64 + c];
      *(float4*)&bs_[r][c] = *(const float4*)&vb[(size_t)(kt * 64 + r) * VDN + c];
    }
    __syncthreads();
#pragma unroll 4
    for (int dd = 0; dd < 64; ++dd) {
      float a[4];
#pragma unroll
      for (int i = 0; i < 4; ++i) a[i] = as_[ty * 4 + i][dd];
      const float4 b4 = *(const float4*)&bs_[dd][tx * 4];
      const float bj[4] = {b4.x, b4.y, b4.z, b4.w};
#pragma unroll
      for (int i = 0; i < 4; ++i)
#pragma unroll
        for (int j = 0; j < 4; ++j)
          acc[i][j] = __fmaf_rn(a[i], bj[j], acc[i][j]);
    }
  }
#pragma unroll
  for (int i = 0; i < 4; ++i) {
    const size_t off = ((size_t)(n * SL + q0 + ty * 4 + i)) * ODN + h * VDN + tx * 4;
    float4 cur = *(float4*)&y[off];
    cur.x += 0.5f * acc[i][0];
    cur.y += 0.5f * acc[i][1];
    cur.z += 0.5f * acc[i][2];
    cur.w += 0.5f * acc[i][3];
    *(float4*)&y[off] = cur;
  }
}

// ------------------------------------------------- out = y @ Wout + bout ---
__global__ __launch_bounds__(256) void out_kernel(
    const float* __restrict__ Wout, const float* __restrict__ bout,
    const float* __restrict__ ws, float* __restrict__ out)
{
  __shared__ float as_[64][68];
  __shared__ float bs_[64][68];
  const int tid = threadIdx.x;
  const int tx = tid & 15, ty = tid >> 4;
  const int od0 = blockIdx.x * 64;
  const int m0 = blockIdx.y * 64;
  const float* y = ws + Y_OFF;
  float acc[4][4] = {{0.f}};
  for (int kt = 0; kt < 8; ++kt) {
    __syncthreads();
#pragma unroll
    for (int it = 0; it < 4; ++it) {
      const int r = ty + it * 16;
      const int c = tx * 4;
      *(float4*)&as_[r][c] = *(const float4*)&y[(size_t)(m0 + r) * ODN + kt * 64 + c];
      *(float4*)&bs_[r][c] = *(const float4*)&Wout[(size_t)(kt * 64 + r) * ODN + od0 + c];
    }
    __syncthreads();
#pragma unroll 4
    for (int dd = 0; dd < 64; ++dd) {
      float a[4];
#pragma unroll
      for (int i = 0; i < 4; ++i) a[i] = as_[ty * 4 + i][dd];
      const float4 b4 = *(const float4*)&bs_[dd][tx * 4];
      const float bj[4] = {b4.x, b4.y, b4.z, b4.w};
#pragma unroll
      for (int i = 0; i < 4; ++i)
#pragma unroll
        for (int j = 0; j < 4; ++j)
          acc[i][j] = __fmaf_rn(a[i], bj[j], acc[i][j]);
    }
  }
#pragma unroll
  for (int i = 0; i < 4; ++i) {
    float4 o4;
    o4.x = acc[i][0] + bout[od0 + tx * 4 + 0];
    o4.y = acc[i][1] + bout[od0 + tx * 4 + 1];
    o4.z = acc[i][2] + bout[od0 + tx * 4 + 2];
    o4.w = acc[i][3] + bout[od0 + tx * 4 + 3];
    *(float4*)&out[(size_t)(m0 + ty * 4 + i) * ODN + od0 + tx * 4] = o4;
  }
}

extern "C" void kernel_launch(void* const* d_in, const int* in_sizes, int n_in,
                              void* d_out, int out_size, void* d_ws, size_t ws_size,
                              hipStream_t stream)
{
  const float* x     = (const float*)d_in[0];
  const float* Wk    = (const float*)d_in[1];
  const float* bk    = (const float*)d_in[2];
  const float* Wv    = (const float*)d_in[3];
  const float* bv    = (const float*)d_in[4];
  const float* Wout  = (const float*)d_in[5];
  const float* bout  = (const float*)d_in[6];
  const float* graph = (const float*)d_in[7];
  const int*   knn   = (const int*)d_in[8];
  float* out = (float*)d_out;
  float* ws  = (float*)d_ws;

  kvproj_kernel<<<dim3(128, 8), 256, 0, stream>>>(x, Wk, bk, Wv, bv, ws);
  gsoftmax_kernel<<<dim3(1024), 256, 0, stream>>>(graph, ws);
  attn_kernel<<<dim3(64, 64), 256, 0, stream>>>(ws, knn);
  gv_kernel<<<dim3(16, 64), 256, 0, stream>>>(ws);
  out_kernel<<<dim3(8, 128), 256, 0, stream>>>(Wout, bout, ws, out);
}

// Round 3
// 598.868 us; speedup vs baseline: 1.1757x; 1.0301x over previous
//
#include <hip/hip_runtime.h>
#include <math.h>

#define NB 8
#define SL 1024
#define DI 512
#define HH 8
#define KDN 64
#define VDN 64
#define ODN 512
#define ATT_SCALE 0.125f

// workspace layout (float units)
// KHI (bf16): [H*N][S][KD] at ushort offset 0 -> 4,194,304 ushorts = 2,097,152 f
#define KLO_OFF 2097152u   // bf16 lo plane, same shape            8 MB
#define V_OFF   4194304u   // [H*N][S][VD] f32                    16 MB
#define G_OFF   8388608u   // [S][S] f32                           4 MB
#define Y_OFF   9437184u   // [N][S][H*VD] f32                    16 MB
// total 13,631,488 floats = 52 MB

#define ORD_NEG_INF 0x007FFFFFu

typedef __attribute__((ext_vector_type(8))) short bf16x8;
typedef __attribute__((ext_vector_type(4))) float f32x4;

__device__ __forceinline__ unsigned fordu(float f) {
  unsigned b = __float_as_uint(f);
  return b ^ ((b & 0x80000000u) ? 0xFFFFFFFFu : 0x80000000u);
}
__device__ __forceinline__ float ifordu(unsigned k) {
  unsigned b = k ^ ((k & 0x80000000u) ? 0x80000000u : 0xFFFFFFFFu);
  return __uint_as_float(b);
}
__device__ __forceinline__ unsigned short f2bf(float f) {  // RNE f32->bf16
  unsigned u = __float_as_uint(f);
  unsigned r = (u + 0x7FFFu + ((u >> 16) & 1u)) >> 16;
  return (unsigned short)r;
}

// ---------------------------------------------------------------- kv proj ---
__global__ __launch_bounds__(256) void kvproj_kernel(
    const float* __restrict__ x, const float* __restrict__ Wk, const float* __restrict__ bk,
    const float* __restrict__ Wv, const float* __restrict__ bv, float* __restrict__ ws)
{
  __shared__ float xs[64][68];
  __shared__ float wks[64][68];
  __shared__ float wvs[64][68];
  const int tid = threadIdx.x;
  const int tx = tid & 15, ty = tid >> 4;
  const int m0 = blockIdx.x * 64;
  const int h = blockIdx.y;
  const float* wkb = Wk + (size_t)h * (DI * KDN);
  const float* wvb = Wv + (size_t)h * (DI * VDN);
  float ak[4][4] = {{0.f}};
  float av[4][4] = {{0.f}};
  for (int dt = 0; dt < DI / 64; ++dt) {
    __syncthreads();
#pragma unroll
    for (int it = 0; it < 4; ++it) {
      const int r = ty + it * 16;
      const int c = tx * 4;
      *(float4*)&xs[r][c]  = *(const float4*)&x[(size_t)(m0 + r) * DI + dt * 64 + c];
      *(float4*)&wks[r][c] = *(const float4*)&wkb[(size_t)(dt * 64 + r) * KDN + c];
      *(float4*)&wvs[r][c] = *(const float4*)&wvb[(size_t)(dt * 64 + r) * VDN + c];
    }
    __syncthreads();
#pragma unroll 4
    for (int dd = 0; dd < 64; ++dd) {
      float a[4];
#pragma unroll
      for (int i = 0; i < 4; ++i) a[i] = xs[ty * 4 + i][dd];
      const float4 bkv = *(const float4*)&wks[dd][tx * 4];
      const float4 bvv = *(const float4*)&wvs[dd][tx * 4];
      const float bkj[4] = {bkv.x, bkv.y, bkv.z, bkv.w};
      const float bvj[4] = {bvv.x, bvv.y, bvv.z, bvv.w};
#pragma unroll
      for (int i = 0; i < 4; ++i) {
#pragma unroll
        for (int j = 0; j < 4; ++j) {
          ak[i][j] = __fmaf_rn(a[i], bkj[j], ak[i][j]);
          av[i][j] = __fmaf_rn(a[i], bvj[j], av[i][j]);
        }
      }
    }
  }
  const int n = m0 >> 10;
  const int s0 = m0 & 1023;
  float* vb = ws + V_OFF;
  unsigned short* khi = (unsigned short*)ws;
  unsigned short* klo = (unsigned short*)(ws + KLO_OFF);
#pragma unroll
  for (int i = 0; i < 4; ++i) {
    const int s = s0 + ty * 4 + i;
    float4 vv;
    vv.x = av[i][0] + bv[h * VDN + tx * 4 + 0];
    vv.y = av[i][1] + bv[h * VDN + tx * 4 + 1];
    vv.z = av[i][2] + bv[h * VDN + tx * 4 + 2];
    vv.w = av[i][3] + bv[h * VDN + tx * 4 + 3];
    *(float4*)&vb[((size_t)(h * NB + n) * SL + s) * VDN + tx * 4] = vv;
    union { unsigned short u[4]; uint2 v2; } ph, pl;
#pragma unroll
    for (int j = 0; j < 4; ++j) {
      const float kf = ak[i][j] + bk[h * KDN + tx * 4 + j];
      const unsigned short h16 = f2bf(kf);
      const float hf = __uint_as_float(((unsigned)h16) << 16);
      ph.u[j] = h16;
      pl.u[j] = f2bf(kf - hf);
    }
    const size_t koff = ((size_t)(h * NB + n) * SL + s) * KDN + tx * 4;
    *(uint2*)&khi[koff] = ph.v2;
    *(uint2*)&klo[koff] = pl.v2;
  }
}

// ---------------------------------------------------------- graph softmax ---
__global__ __launch_bounds__(256) void gsoftmax_kernel(const float* __restrict__ gin, float* __restrict__ ws)
{
  float* gout = ws + G_OFF;
  const int row = blockIdx.x;
  const int tid = threadIdx.x;
  const int lane = tid & 63, wave = tid >> 6;
  __shared__ float red[4];
  __shared__ float red2[4];
  float v[4];
  float m = -INFINITY;
#pragma unroll
  for (int i = 0; i < 4; ++i) {
    v[i] = gin[(size_t)row * SL + tid + i * 256];
    m = fmaxf(m, v[i]);
  }
#pragma unroll
  for (int off = 32; off; off >>= 1) m = fmaxf(m, __shfl_xor(m, off));
  if (lane == 0) red[wave] = m;
  __syncthreads();
  m = fmaxf(fmaxf(red[0], red[1]), fmaxf(red[2], red[3]));
  float e[4];
  float s = 0.f;
#pragma unroll
  for (int i = 0; i < 4; ++i) { e[i] = __expf(v[i] - m); s += e[i]; }
#pragma unroll
  for (int off = 32; off; off >>= 1) s += __shfl_xor(s, off);
  if (lane == 0) red2[wave] = s;
  __syncthreads();
  s = red2[0] + red2[1] + red2[2] + red2[3];
  const float inv = 1.0f / s;
#pragma unroll
  for (int i = 0; i < 4; ++i) gout[(size_t)row * SL + tid + i * 256] = e[i] * inv;
}

// -------------------------------------------------------------- attention ---
// block: 256 thr (4 waves), 16 q-rows, one (h,n).
// split-bf16 QK^T via MFMA -> LDS score strip (2 phases) -> per-wave register
// rows -> branchless binary-search exact top-K -> softmax -> sparse PV.
__global__ __launch_bounds__(256, 4) void attn_kernel(float* __restrict__ ws, const int* __restrict__ knn_p)
{
  __shared__ float S[16][516];    // 33 KB; reused as per-wave compaction lists
  const int tid = threadIdx.x;
  const int lane = tid & 63;
  const int wave = tid >> 6;
  const int q0 = blockIdx.x * 16;
  const int hn = blockIdx.y;
  const int h = hn >> 3, n = hn & 7;
  const int K = knn_p[0];
  const unsigned short* khi = (const unsigned short*)ws + (size_t)hn * SL * KDN;
  const unsigned short* klo = (const unsigned short*)(ws + KLO_OFF) + (size_t)hn * SL * KDN;
  const float* vb = ws + V_OFF + (size_t)hn * (SL * VDN);
  float* y = ws + Y_OFF;

  const int col = lane & 15, grp = lane >> 4;
  const bf16x8 a0h = *(const bf16x8*)&khi[(size_t)(q0 + col) * KDN + grp * 8];
  const bf16x8 a1h = *(const bf16x8*)&khi[(size_t)(q0 + col) * KDN + 32 + grp * 8];
  const bf16x8 a0l = *(const bf16x8*)&klo[(size_t)(q0 + col) * KDN + grp * 8];
  const bf16x8 a1l = *(const bf16x8*)&klo[(size_t)(q0 + col) * KDN + 32 + grp * 8];

  const int T = q0 / 16 + 1;      // causal t-tiles needed
  const int rbase = wave * 4;

  float ev[4][8][2];              // per-row keys (later e-values), static-indexed
#pragma unroll
  for (int rr = 0; rr < 4; ++rr)
#pragma unroll
    for (int c = 0; c < 8; ++c) {
      ev[rr][c][0] = __uint_as_float(ORD_NEG_INF);
      ev[rr][c][1] = __uint_as_float(ORD_NEG_INF);
    }

#pragma unroll
  for (int ph = 0; ph < 2; ++ph) {
    const int tlo = ph * 32;
    const int thi = (T < tlo + 32) ? T : (tlo + 32);
    if (thi > tlo) {            // block-uniform
      __syncthreads();
      for (int ti = tlo + wave; ti < thi; ti += 4) {
        const int t0 = ti * 16;
        const size_t bo = (size_t)(t0 + col) * KDN + grp * 8;
        const bf16x8 b0h = *(const bf16x8*)&khi[bo];
        const bf16x8 b1h = *(const bf16x8*)&khi[bo + 32];
        const bf16x8 b0l = *(const bf16x8*)&klo[bo];
        const bf16x8 b1l = *(const bf16x8*)&klo[bo + 32];
        f32x4 d = {0.f, 0.f, 0.f, 0.f};
        d = __builtin_amdgcn_mfma_f32_16x16x32_bf16(a0h, b0h, d, 0, 0, 0);
        d = __builtin_amdgcn_mfma_f32_16x16x32_bf16(a1h, b1h, d, 0, 0, 0);
        d = __builtin_amdgcn_mfma_f32_16x16x32_bf16(a0h, b0l, d, 0, 0, 0);
        d = __builtin_amdgcn_mfma_f32_16x16x32_bf16(a1h, b1l, d, 0, 0, 0);
        d = __builtin_amdgcn_mfma_f32_16x16x32_bf16(a0l, b0h, d, 0, 0, 0);
        d = __builtin_amdgcn_mfma_f32_16x16x32_bf16(a1l, b1h, d, 0, 0, 0);
        d = __builtin_amdgcn_mfma_f32_16x16x32_bf16(a0l, b0l, d, 0, 0, 0);
        d = __builtin_amdgcn_mfma_f32_16x16x32_bf16(a1l, b1l, d, 0, 0, 0);
        const int tl = t0 - ph * 512 + col;
#pragma unroll
        for (int r = 0; r < 4; ++r) S[grp * 4 + r][tl] = d[r];
      }
      __syncthreads();
#pragma unroll
      for (int rr = 0; rr < 4; ++rr) {
        const int q = q0 + rbase + rr;
        const int cmr = q >> 7;
#pragma unroll
        for (int cc = 0; cc < 4; ++cc) {
          const int c = ph * 4 + cc;
          if (c <= cmr) {
            const float2 sv = *(const float2*)&S[rbase + rr][cc * 128 + lane * 2];
            const int t0 = c * 128 + lane * 2;
            const unsigned k0 = (t0     <= q) ? fordu(sv.x * ATT_SCALE) : ORD_NEG_INF;
            const unsigned k1 = (t0 + 1 <= q) ? fordu(sv.y * ATT_SCALE) : ORD_NEG_INF;
            ev[rr][c][0] = __uint_as_float(k0);
            ev[rr][c][1] = __uint_as_float(k1);
          }
        }
      }
    }
  }
  __syncthreads();  // all rows captured -> reuse S as per-wave scratch

  float* elist = &S[0][0] + wave * 1536;                   // 1024 e-values
  unsigned short* tlist = (unsigned short*)(elist + 1024); // 1024 t-indices

#pragma unroll
  for (int rr = 0; rr < 4; ++rr) {
    const int q = q0 + rbase + rr;

    unsigned u[16];
#pragma unroll
    for (int c = 0; c < 8; ++c) {
      u[c * 2]     = __float_as_uint(ev[rr][c][0]);
      u[c * 2 + 1] = __float_as_uint(ev[rr][c][1]);
    }

    // lane-max, then wave max (mk) and wave min-of-lane-maxes (t0k).
    unsigned lmax = u[0];
#pragma unroll
    for (int i = 1; i < 16; ++i) lmax = lmax > u[i] ? lmax : u[i];
    unsigned mk = lmax, t0k = lmax;
#pragma unroll
    for (int off = 32; off; off >>= 1) {
      const unsigned om = (unsigned)__shfl_xor((int)mk, off);
      const unsigned ot = (unsigned)__shfl_xor((int)t0k, off);
      mk = mk > om ? mk : om;
      t0k = t0k < ot ? t0k : ot;
    }
    const float m = ifordu(mk);

    // exact Kth-largest key: binary search on rank over u32 key space.
    // rank(t0k) >= 64 (each lane's max >= t0k) so for K<=64 search [t0k, mk].
    unsigned kth;
    if (q < K) {
      kth = ORD_NEG_INF;   // keep all (padding keys give e=0 naturally)
    } else {
      unsigned lo = (K <= 64) ? t0k : 0u;
      unsigned hi = mk;
      while (lo < hi) {
        const unsigned mid = lo + ((hi - lo + 1) >> 1);
        int cnt = 0;
#pragma unroll
        for (int i = 0; i < 16; ++i)
          cnt += (int)__popcll(__ballot(u[i] >= mid));
        if (cnt >= K) lo = mid; else hi = mid - 1;
      }
      kth = lo;
    }

    // e = exp(att - m) for kept entries; Z. (padding: ifordu=-inf -> e=0)
    float Z = 0.f;
#pragma unroll
    for (int c = 0; c < 8; ++c) {
#pragma unroll
      for (int j = 0; j < 2; ++j) {
        const unsigned k = u[c * 2 + j];
        float e = 0.f;
        if (k >= kth) e = __expf(ifordu(k) - m);
        ev[rr][c][j] = e;
        Z += e;
      }
    }
#pragma unroll
    for (int off = 32; off; off >>= 1) Z += __shfl_xor(Z, off);

    // compact kept (e>0) entries into per-wave LDS lists
    int cnt = 0;
#pragma unroll
    for (int c = 0; c < 8; ++c) {
#pragma unroll
      for (int j = 0; j < 2; ++j) {
        const float e = ev[rr][c][j];
        const unsigned long long msk = __ballot(e > 0.f);
        if (e > 0.f) {
          const int pos = cnt + (int)__popcll(msk & ((1ull << lane) - 1ull));
          elist[pos] = e;
          tlist[pos] = (unsigned short)(c * 128 + lane * 2 + j);
        }
        cnt += (int)__popcll(msk);
      }
    }

    // sparse PV: lane = vd
    float yacc = 0.f;
    int i2 = 0;
    for (; i2 + 4 <= cnt; i2 += 4) {
      const float4 e4 = *(const float4*)&elist[i2];
      const ushort4 t4 = *(const ushort4*)&tlist[i2];
      yacc = __fmaf_rn(e4.x, vb[(size_t)t4.x * VDN + lane], yacc);
      yacc = __fmaf_rn(e4.y, vb[(size_t)t4.y * VDN + lane], yacc);
      yacc = __fmaf_rn(e4.z, vb[(size_t)t4.z * VDN + lane], yacc);
      yacc = __fmaf_rn(e4.w, vb[(size_t)t4.w * VDN + lane], yacc);
    }
    for (; i2 < cnt; ++i2) {
      yacc = __fmaf_rn(elist[i2], vb[(size_t)tlist[i2] * VDN + lane], yacc);
    }
    y[((size_t)(n * SL + q)) * ODN + h * VDN + lane] = yacc * (0.5f / Z);
  }
}

// ----------------------------------------------------- y += 0.5 * (g @ v) ---
__global__ __launch_bounds__(256) void gv_kernel(float* __restrict__ ws)
{
  __shared__ float as_[64][68];
  __shared__ float bs_[64][68];
  const int tid = threadIdx.x;
  const int tx = tid & 15, ty = tid >> 4;
  const int q0 = blockIdx.x * 64;
  const int hn = blockIdx.y;
  const int h = hn >> 3, n = hn & 7;
  const float* g = ws + G_OFF;
  const float* vb = ws + V_OFF + (size_t)hn * (SL * VDN);
  float* y = ws + Y_OFF;
  float acc[4][4] = {{0.f}};
  for (int kt = 0; kt < 16; ++kt) {
    __syncthreads();
#pragma unroll
    for (int it = 0; it < 4; ++it) {
      const int r = ty + it * 16;
      const int c = tx * 4;
      *(float4*)&as_[r][c] = *(const float4*)&g[(size_t)(q0 + r) * SL + kt * 64 + c];
      *(float4*)&bs_[r][c] = *(const float4*)&vb[(size_t)(kt * 64 + r) * VDN + c];
    }
    __syncthreads();
#pragma unroll 4
    for (int dd = 0; dd < 64; ++dd) {
      float a[4];
#pragma unroll
      for (int i = 0; i < 4; ++i) a[i] = as_[ty * 4 + i][dd];
      const float4 b4 = *(const float4*)&bs_[dd][tx * 4];
      const float bj[4] = {b4.x, b4.y, b4.z, b4.w};
#pragma unroll
      for (int i = 0; i < 4; ++i)
#pragma unroll
        for (int j = 0; j < 4; ++j)
          acc[i][j] = __fmaf_rn(a[i], bj[j], acc[i][j]);
    }
  }
#pragma unroll
  for (int i = 0; i < 4; ++i) {
    const size_t off = ((size_t)(n * SL + q0 + ty * 4 + i)) * ODN + h * VDN + tx * 4;
    float4 cur = *(float4*)&y[off];
    cur.x += 0.5f * acc[i][0];
    cur.y += 0.5f * acc[i][1];
    cur.z += 0.5f * acc[i][2];
    cur.w += 0.5f * acc[i][3];
    *(float4*)&y[off] = cur;
  }
}

// ------------------------------------------------- out = y @ Wout + bout ---
__global__ __launch_bounds__(256) void out_kernel(
    const float* __restrict__ Wout, const float* __restrict__ bout,
    const float* __restrict__ ws, float* __restrict__ out)
{
  __shared__ float as_[64][68];
  __shared__ float bs_[64][68];
  const int tid = threadIdx.x;
  const int tx = tid & 15, ty = tid >> 4;
  const int od0 = blockIdx.x * 64;
  const int m0 = blockIdx.y * 64;
  const float* y = ws + Y_OFF;
  float acc[4][4] = {{0.f}};
  for (int kt = 0; kt < 8; ++kt) {
    __syncthreads();
#pragma unroll
    for (int it = 0; it < 4; ++it) {
      const int r = ty + it * 16;
      const int c = tx * 4;
      *(float4*)&as_[r][c] = *(const float4*)&y[(size_t)(m0 + r) * ODN + kt * 64 + c];
      *(float4*)&bs_[r][c] = *(const float4*)&Wout[(size_t)(kt * 64 + r) * ODN + od0 + c];
    }
    __syncthreads();
#pragma unroll 4
    for (int dd = 0; dd < 64; ++dd) {
      float a[4];
#pragma unroll
      for (int i = 0; i < 4; ++i) a[i] = as_[ty * 4 + i][dd];
      const float4 b4 = *(const float4*)&bs_[dd][tx * 4];
      const float bj[4] = {b4.x, b4.y, b4.z, b4.w};
#pragma unroll
      for (int i = 0; i < 4; ++i)
#pragma unroll
        for (int j = 0; j < 4; ++j)
          acc[i][j] = __fmaf_rn(a[i], bj[j], acc[i][j]);
    }
  }
#pragma unroll
  for (int i = 0; i < 4; ++i) {
    float4 o4;
    o4.x = acc[i][0] + bout[od0 + tx * 4 + 0];
    o4.y = acc[i][1] + bout[od0 + tx * 4 + 1];
    o4.z = acc[i][2] + bout[od0 + tx * 4 + 2];
    o4.w = acc[i][3] + bout[od0 + tx * 4 + 3];
    *(float4*)&out[(size_t)(m0 + ty * 4 + i) * ODN + od0 + tx * 4] = o4;
  }
}

extern "C" void kernel_launch(void* const* d_in, const int* in_sizes, int n_in,
                              void* d_out, int out_size, void* d_ws, size_t ws_size,
                              hipStream_t stream)
{
  const float* x     = (const float*)d_in[0];
  const float* Wk    = (const float*)d_in[1];
  const float* bk    = (const float*)d_in[2];
  const float* Wv    = (const float*)d_in[3];
  const float* bv    = (const float*)d_in[4];
  const float* Wout  = (const float*)d_in[5];
  const float* bout  = (const float*)d_in[6];
  const float* graph = (const float*)d_in[7];
  const int*   knn   = (const int*)d_in[8];
  float* out = (float*)d_out;
  float* ws  = (float*)d_ws;

  kvproj_kernel<<<dim3(128, 8), 256, 0, stream>>>(x, Wk, bk, Wv, bv, ws);
  gsoftmax_kernel<<<dim3(1024), 256, 0, stream>>>(graph, ws);
  attn_kernel<<<dim3(64, 64), 256, 0, stream>>>(ws, knn);
  gv_kernel<<<dim3(16, 64), 256, 0, stream>>>(ws);
  out_kernel<<<dim3(8, 128), 256, 0, stream>>>(Wout, bout, ws, out);
}

// Round 5
// 569.978 us; speedup vs baseline: 1.2353x; 1.0507x over previous
//
#include <hip/hip_runtime.h>
#include <math.h>

#define NB 8
#define SL 1024
#define DI 512
#define HH 8
#define KDN 64
#define VDN 64
#define ODN 512
#define ATT_SCALE 0.125f

// workspace layout (float units)
// KHI (bf16): [H*N][S][KD] at ushort offset 0 -> 4,194,304 ushorts = 2,097,152 f
#define KLO_OFF 2097152u   // bf16 lo plane, same shape            8 MB
#define V_OFF   4194304u   // [H*N][S][VD] f32                    16 MB
#define G_OFF   8388608u   // [S][S] f32                           4 MB
#define Y_OFF   9437184u   // [N][S][H*VD] f32                    16 MB

#define ORD_NEG_INF 0x007FFFFFu

typedef __attribute__((ext_vector_type(8))) short bf16x8;
typedef __attribute__((ext_vector_type(4))) float f32x4;

__device__ __forceinline__ unsigned fordu(float f) {
  unsigned b = __float_as_uint(f);
  return b ^ ((b & 0x80000000u) ? 0xFFFFFFFFu : 0x80000000u);
}
__device__ __forceinline__ float ifordu(unsigned k) {
  unsigned b = k ^ ((k & 0x80000000u) ? 0x80000000u : 0xFFFFFFFFu);
  return __uint_as_float(b);
}
__device__ __forceinline__ unsigned short f2bf(float f) {  // RNE f32->bf16
  unsigned u = __float_as_uint(f);
  unsigned r = (u + 0x7FFFu + ((u >> 16) & 1u)) >> 16;
  return (unsigned short)r;
}

// ---------------------------------------------------------------- kv proj ---
__global__ __launch_bounds__(256) void kvproj_kernel(
    const float* __restrict__ x, const float* __restrict__ Wk, const float* __restrict__ bk,
    const float* __restrict__ Wv, const float* __restrict__ bv, float* __restrict__ ws)
{
  __shared__ float xs[64][68];
  __shared__ float wks[64][68];
  __shared__ float wvs[64][68];
  const int tid = threadIdx.x;
  const int tx = tid & 15, ty = tid >> 4;
  const int m0 = blockIdx.x * 64;
  const int h = blockIdx.y;
  const float* wkb = Wk + (size_t)h * (DI * KDN);
  const float* wvb = Wv + (size_t)h * (DI * VDN);
  float ak[4][4] = {{0.f}};
  float av[4][4] = {{0.f}};
  for (int dt = 0; dt < DI / 64; ++dt) {
    __syncthreads();
#pragma unroll
    for (int it = 0; it < 4; ++it) {
      const int r = ty + it * 16;
      const int c = tx * 4;
      *(float4*)&xs[r][c]  = *(const float4*)&x[(size_t)(m0 + r) * DI + dt * 64 + c];
      *(float4*)&wks[r][c] = *(const float4*)&wkb[(size_t)(dt * 64 + r) * KDN + c];
      *(float4*)&wvs[r][c] = *(const float4*)&wvb[(size_t)(dt * 64 + r) * VDN + c];
    }
    __syncthreads();
#pragma unroll 4
    for (int dd = 0; dd < 64; ++dd) {
      float a[4];
#pragma unroll
      for (int i = 0; i < 4; ++i) a[i] = xs[ty * 4 + i][dd];
      const float4 bkv = *(const float4*)&wks[dd][tx * 4];
      const float4 bvv = *(const float4*)&wvs[dd][tx * 4];
      const float bkj[4] = {bkv.x, bkv.y, bkv.z, bkv.w};
      const float bvj[4] = {bvv.x, bvv.y, bvv.z, bvv.w};
#pragma unroll
      for (int i = 0; i < 4; ++i) {
#pragma unroll
        for (int j = 0; j < 4; ++j) {
          ak[i][j] = __fmaf_rn(a[i], bkj[j], ak[i][j]);
          av[i][j] = __fmaf_rn(a[i], bvj[j], av[i][j]);
        }
      }
    }
  }
  const int n = m0 >> 10;
  const int s0 = m0 & 1023;
  float* vb = ws + V_OFF;
  unsigned short* khi = (unsigned short*)ws;
  unsigned short* klo = (unsigned short*)(ws + KLO_OFF);
#pragma unroll
  for (int i = 0; i < 4; ++i) {
    const int s = s0 + ty * 4 + i;
    float4 vv;
    vv.x = av[i][0] + bv[h * VDN + tx * 4 + 0];
    vv.y = av[i][1] + bv[h * VDN + tx * 4 + 1];
    vv.z = av[i][2] + bv[h * VDN + tx * 4 + 2];
    vv.w = av[i][3] + bv[h * VDN + tx * 4 + 3];
    *(float4*)&vb[((size_t)(h * NB + n) * SL + s) * VDN + tx * 4] = vv;
    union { unsigned short u[4]; uint2 v2; } ph, pl;
#pragma unroll
    for (int j = 0; j < 4; ++j) {
      const float kf = ak[i][j] + bk[h * KDN + tx * 4 + j];
      const unsigned short h16 = f2bf(kf);
      const float hf = __uint_as_float(((unsigned)h16) << 16);
      ph.u[j] = h16;
      pl.u[j] = f2bf(kf - hf);
    }
    const size_t koff = ((size_t)(h * NB + n) * SL + s) * KDN + tx * 4;
    *(uint2*)&khi[koff] = ph.v2;
    *(uint2*)&klo[koff] = pl.v2;
  }
}

// ---------------------------------------------------------- graph softmax ---
__global__ __launch_bounds__(256) void gsoftmax_kernel(const float* __restrict__ gin, float* __restrict__ ws)
{
  float* gout = ws + G_OFF;
  const int row = blockIdx.x;
  const int tid = threadIdx.x;
  const int lane = tid & 63, wave = tid >> 6;
  __shared__ float red[4];
  __shared__ float red2[4];
  float v[4];
  float m = -INFINITY;
#pragma unroll
  for (int i = 0; i < 4; ++i) {
    v[i] = gin[(size_t)row * SL + tid + i * 256];
    m = fmaxf(m, v[i]);
  }
#pragma unroll
  for (int off = 32; off; off >>= 1) m = fmaxf(m, __shfl_xor(m, off));
  if (lane == 0) red[wave] = m;
  __syncthreads();
  m = fmaxf(fmaxf(red[0], red[1]), fmaxf(red[2], red[3]));
  float e[4];
  float s = 0.f;
#pragma unroll
  for (int i = 0; i < 4; ++i) { e[i] = __expf(v[i] - m); s += e[i]; }
#pragma unroll
  for (int off = 32; off; off >>= 1) s += __shfl_xor(s, off);
  if (lane == 0) red2[wave] = s;
  __syncthreads();
  s = red2[0] + red2[1] + red2[2] + red2[3];
  const float inv = 1.0f / s;
#pragma unroll
  for (int i = 0; i < 4; ++i) gout[(size_t)row * SL + tid + i * 256] = e[i] * inv;
}

// -------------------------------------------------------------- attention ---
// block: 256 thr (4 waves), 16 q-rows, one (h,n). Round-3 structure (verified),
// with a 4-phase [16][260] strip (16.6 KB LDS) for 8 blocks/CU occupancy and
// capped-128 compaction lists inside the dead strip.
__global__ __launch_bounds__(256, 8) void attn_kernel(float* __restrict__ ws, const int* __restrict__ knn_p)
{
  __shared__ float S[16][260];    // 16.6 KB; reused as per-wave lists after capture
  const int tid = threadIdx.x;
  const int lane = tid & 63;
  const int wave = tid >> 6;
  const int q0 = blockIdx.x * 16;
  const int hn = blockIdx.y;
  const int h = hn >> 3, n = hn & 7;
  const int K = knn_p[0];
  const unsigned short* khi = (const unsigned short*)ws + (size_t)hn * SL * KDN;
  const unsigned short* klo = (const unsigned short*)(ws + KLO_OFF) + (size_t)hn * SL * KDN;
  const float* vb = ws + V_OFF + (size_t)hn * (SL * VDN);
  float* y = ws + Y_OFF;

  const int col = lane & 15, grp = lane >> 4;
  const bf16x8 a0h = *(const bf16x8*)&khi[(size_t)(q0 + col) * KDN + grp * 8];
  const bf16x8 a1h = *(const bf16x8*)&khi[(size_t)(q0 + col) * KDN + 32 + grp * 8];
  const bf16x8 a0l = *(const bf16x8*)&klo[(size_t)(q0 + col) * KDN + grp * 8];
  const bf16x8 a1l = *(const bf16x8*)&klo[(size_t)(q0 + col) * KDN + 32 + grp * 8];

  const int T = q0 / 16 + 1;      // causal t-tiles needed
  const int rbase = wave * 4;

  float ev[4][8][2];              // per-row keys (later e-values), static-indexed
#pragma unroll
  for (int rr = 0; rr < 4; ++rr)
#pragma unroll
    for (int c = 0; c < 8; ++c) {
      ev[rr][c][0] = __uint_as_float(ORD_NEG_INF);
      ev[rr][c][1] = __uint_as_float(ORD_NEG_INF);
    }

#pragma unroll
  for (int ph = 0; ph < 4; ++ph) {
    const int tlo = ph * 16;
    const int thi = (T < tlo + 16) ? T : (tlo + 16);
    if (thi > tlo) {            // block-uniform
      __syncthreads();
      for (int ti = tlo + wave; ti < thi; ti += 4) {
        const int t0 = ti * 16;
        const size_t bo = (size_t)(t0 + col) * KDN + grp * 8;
        const bf16x8 b0h = *(const bf16x8*)&khi[bo];
        const bf16x8 b1h = *(const bf16x8*)&khi[bo + 32];
        const bf16x8 b0l = *(const bf16x8*)&klo[bo];
        const bf16x8 b1l = *(const bf16x8*)&klo[bo + 32];
        f32x4 d = {0.f, 0.f, 0.f, 0.f};
        d = __builtin_amdgcn_mfma_f32_16x16x32_bf16(a0h, b0h, d, 0, 0, 0);
        d = __builtin_amdgcn_mfma_f32_16x16x32_bf16(a1h, b1h, d, 0, 0, 0);
        d = __builtin_amdgcn_mfma_f32_16x16x32_bf16(a0h, b0l, d, 0, 0, 0);
        d = __builtin_amdgcn_mfma_f32_16x16x32_bf16(a1h, b1l, d, 0, 0, 0);
        d = __builtin_amdgcn_mfma_f32_16x16x32_bf16(a0l, b0h, d, 0, 0, 0);
        d = __builtin_amdgcn_mfma_f32_16x16x32_bf16(a1l, b1h, d, 0, 0, 0);
        d = __builtin_amdgcn_mfma_f32_16x16x32_bf16(a0l, b0l, d, 0, 0, 0);
        d = __builtin_amdgcn_mfma_f32_16x16x32_bf16(a1l, b1l, d, 0, 0, 0);
        const int tl = t0 - ph * 256 + col;
#pragma unroll
        for (int r = 0; r < 4; ++r) S[grp * 4 + r][tl] = d[r];
      }
      __syncthreads();
#pragma unroll
      for (int rr = 0; rr < 4; ++rr) {
        const int q = q0 + rbase + rr;
        const int cmr = q >> 7;
#pragma unroll
        for (int cc = 0; cc < 2; ++cc) {
          const int c = ph * 2 + cc;
          if (c <= cmr) {
            const float2 sv = *(const float2*)&S[rbase + rr][cc * 128 + lane * 2];
            const int t0 = c * 128 + lane * 2;
            const unsigned k0 = (t0     <= q) ? fordu(sv.x * ATT_SCALE) : ORD_NEG_INF;
            const unsigned k1 = (t0 + 1 <= q) ? fordu(sv.y * ATT_SCALE) : ORD_NEG_INF;
            ev[rr][c][0] = __uint_as_float(k0);
            ev[rr][c][1] = __uint_as_float(k1);
          }
        }
      }
    }
  }
  __syncthreads();  // all rows captured -> reuse S as per-wave scratch

  float* elist = (float*)((char*)&S[0][0] + wave * 768);   // 128 f32
  unsigned short* tlist = (unsigned short*)(elist + 128);  // 128 u16

#pragma unroll
  for (int rr = 0; rr < 4; ++rr) {
    const int q = q0 + rbase + rr;

    unsigned u[16];
#pragma unroll
    for (int c = 0; c < 8; ++c) {
      u[c * 2]     = __float_as_uint(ev[rr][c][0]);
      u[c * 2 + 1] = __float_as_uint(ev[rr][c][1]);
    }

    // lane-max, then wave max (mk) and wave min-of-lane-maxes (t0k).
    unsigned lmax = u[0];
#pragma unroll
    for (int i = 1; i < 16; ++i) lmax = lmax > u[i] ? lmax : u[i];
    unsigned mk = lmax, t0k = lmax;
#pragma unroll
    for (int off = 32; off; off >>= 1) {
      const unsigned om = (unsigned)__shfl_xor((int)mk, off);
      const unsigned ot = (unsigned)__shfl_xor((int)t0k, off);
      mk = mk > om ? mk : om;
      t0k = t0k < ot ? t0k : ot;
    }
    const float m = ifordu(mk);

    // exact Kth-largest key: binary search on rank over u32 key space.
    // rank(t0k) >= 64 (each lane's max >= t0k) so for K<=64 search [t0k, mk].
    unsigned kth;
    if (q < K) {
      kth = ORD_NEG_INF;   // keep all (padding keys give e=0 naturally)
    } else {
      unsigned lo = (K <= 64) ? t0k : 0u;
      unsigned hi = mk;
      while (lo < hi) {
        const unsigned mid = lo + ((hi - lo + 1) >> 1);
        int cnt = 0;
#pragma unroll
        for (int i = 0; i < 16; ++i)
          cnt += (int)__popcll(__ballot(u[i] >= mid));
        if (cnt >= K) lo = mid; else hi = mid - 1;
      }
      kth = lo;
    }

    // e = exp(att - m) for kept entries; Z. (padding: ifordu=-inf -> e=0)
    float Z = 0.f;
#pragma unroll
    for (int c = 0; c < 8; ++c) {
#pragma unroll
      for (int j = 0; j < 2; ++j) {
        const unsigned k = u[c * 2 + j];
        float e = 0.f;
        if (k >= kth) e = __expf(ifordu(k) - m);
        ev[rr][c][j] = e;
        Z += e;
      }
    }
#pragma unroll
    for (int off = 32; off; off >>= 1) Z += __shfl_xor(Z, off);

    // compact kept (e>0) entries into per-wave LDS lists (cap 128; kept
    // count is K + exact ties, so 128 is never exceeded in practice)
    const unsigned long long lt = (1ull << lane) - 1ull;
    int cnt = 0;
#pragma unroll
    for (int c = 0; c < 8; ++c) {
#pragma unroll
      for (int j = 0; j < 2; ++j) {
        const float e = ev[rr][c][j];
        const unsigned long long msk = __ballot(e > 0.f);
        if (e > 0.f) {
          const int pos = cnt + (int)__popcll(msk & lt);
          if (pos < 128) {
            elist[pos] = e;
            tlist[pos] = (unsigned short)(c * 128 + lane * 2 + j);
          }
        }
        cnt += (int)__popcll(msk);
      }
    }
    cnt = (cnt < 128) ? cnt : 128;

    // sparse PV: lane = vd
    float yacc = 0.f;
    int i2 = 0;
    for (; i2 + 4 <= cnt; i2 += 4) {
      const float4 e4 = *(const float4*)&elist[i2];
      const ushort4 t4 = *(const ushort4*)&tlist[i2];
      yacc = __fmaf_rn(e4.x, vb[(size_t)t4.x * VDN + lane], yacc);
      yacc = __fmaf_rn(e4.y, vb[(size_t)t4.y * VDN + lane], yacc);
      yacc = __fmaf_rn(e4.z, vb[(size_t)t4.z * VDN + lane], yacc);
      yacc = __fmaf_rn(e4.w, vb[(size_t)t4.w * VDN + lane], yacc);
    }
    for (; i2 < cnt; ++i2) {
      yacc = __fmaf_rn(elist[i2], vb[(size_t)tlist[i2] * VDN + lane], yacc);
    }
    y[((size_t)(n * SL + q)) * ODN + h * VDN + lane] = yacc * (0.5f / Z);
  }
}

// ----------------------------------------------------- y += 0.5 * (g @ v) ---
__global__ __launch_bounds__(256) void gv_kernel(float* __restrict__ ws)
{
  __shared__ float as_[64][68];
  __shared__ float bs_[64][68];
  const int tid = threadIdx.x;
  const int tx = tid & 15, ty = tid >> 4;
  const int q0 = blockIdx.x * 64;
  const int hn = blockIdx.y;
  const int h = hn >> 3, n = hn & 7;
  const float* g = ws + G_OFF;
  const float* vb = ws + V_OFF + (size_t)hn * (SL * VDN);
  float* y = ws + Y_OFF;
  float acc[4][4] = {{0.f}};
  for (int kt = 0; kt < 16; ++kt) {
    __syncthreads();
#pragma unroll
    for (int it = 0; it < 4; ++it) {
      const int r = ty + it * 16;
      const int c = tx * 4;
      *(float4*)&as_[r][c] = *(const float4*)&g[(size_t)(q0 + r) * SL + kt * 64 + c];
      *(float4*)&bs_[r][c] = *(const float4*)&vb[(size_t)(kt * 64 + r) * VDN + c];
    }
    __syncthreads();
#pragma unroll 4
    for (int dd = 0; dd < 64; ++dd) {
      float a[4];
#pragma unroll
      for (int i = 0; i < 4; ++i) a[i] = as_[ty * 4 + i][dd];
      const float4 b4 = *(const float4*)&bs_[dd][tx * 4];
      const float bj[4] = {b4.x, b4.y, b4.z, b4.w};
#pragma unroll
      for (int i = 0; i < 4; ++i)
#pragma unroll
        for (int j = 0; j < 4; ++j)
          acc[i][j] = __fmaf_rn(a[i], bj[j], acc[i][j]);
    }
  }
#pragma unroll
  for (int i = 0; i < 4; ++i) {
    const size_t off = ((size_t)(n * SL + q0 + ty * 4 + i)) * ODN + h * VDN + tx * 4;
    float4 cur = *(float4*)&y[off];
    cur.x += 0.5f * acc[i][0];
    cur.y += 0.5f * acc[i][1];
    cur.z += 0.5f * acc[i][2];
    cur.w += 0.5f * acc[i][3];
    *(float4*)&y[off] = cur;
  }
}

// ------------------------------------------------- out = y @ Wout + bout ---
__global__ __launch_bounds__(256) void out_kernel(
    const float* __restrict__ Wout, const float* __restrict__ bout,
    const float* __restrict__ ws, float* __restrict__ out)
{
  __shared__ float as_[64][68];
  __shared__ float bs_[64][68];
  const int tid = threadIdx.x;
  const int tx = tid & 15, ty = tid >> 4;
  const int od0 = blockIdx.x * 64;
  const int m0 = blockIdx.y * 64;
  const float* y = ws + Y_OFF;
  float acc[4][4] = {{0.f}};
  for (int kt = 0; kt < 8; ++kt) {
    __syncthreads();
#pragma unroll
    for (int it = 0; it < 4; ++it) {
      const int r = ty + it * 16;
      const int c = tx * 4;
      *(float4*)&as_[r][c] = *(const float4*)&y[(size_t)(m0 + r) * ODN + kt * 64 + c];
      *(float4*)&bs_[r][c] = *(const float4*)&Wout[(size_t)(kt * 64 + r) * ODN + od0 + c];
    }
    __syncthreads();
#pragma unroll 4
    for (int dd = 0; dd < 64; ++dd) {
      float a[4];
#pragma unroll
      for (int i = 0; i < 4; ++i) a[i] = as_[ty * 4 + i][dd];
      const float4 b4 = *(const float4*)&bs_[dd][tx * 4];
      const float bj[4] = {b4.x, b4.y, b4.z, b4.w};
#pragma unroll
      for (int i = 0; i < 4; ++i)
#pragma unroll
        for (int j = 0; j < 4; ++j)
          acc[i][j] = __fmaf_rn(a[i], bj[j], acc[i][j]);
    }
  }
#pragma unroll
  for (int i = 0; i < 4; ++i) {
    float4 o4;
    o4.x = acc[i][0] + bout[od0 + tx * 4 + 0];
    o4.y = acc[i][1] + bout[od0 + tx * 4 + 1];
    o4.z = acc[i][2] + bout[od0 + tx * 4 + 2];
    o4.w = acc[i][3] + bout[od0 + tx * 4 + 3];
    *(float4*)&out[(size_t)(m0 + ty * 4 + i) * ODN + od0 + tx * 4] = o4;
  }
}

extern "C" void kernel_launch(void* const* d_in, const int* in_sizes, int n_in,
                              void* d_out, int out_size, void* d_ws, size_t ws_size,
                              hipStream_t stream)
{
  const float* x     = (const float*)d_in[0];
  const float* Wk    = (const float*)d_in[1];
  const float* bk    = (const float*)d_in[2];
  const float* Wv    = (const float*)d_in[3];
  const float* bv    = (const float*)d_in[4];
  const float* Wout  = (const float*)d_in[5];
  const float* bout  = (const float*)d_in[6];
  const float* graph = (const float*)d_in[7];
  const int*   knn   = (const int*)d_in[8];
  float* out = (float*)d_out;
  float* ws  = (float*)d_ws;

  kvproj_kernel<<<dim3(128, 8), 256, 0, stream>>>(x, Wk, bk, Wv, bv, ws);
  gsoftmax_kernel<<<dim3(1024), 256, 0, stream>>>(graph, ws);
  attn_kernel<<<dim3(64, 64), 256, 0, stream>>>(ws, knn);
  gv_kernel<<<dim3(16, 64), 256, 0, stream>>>(ws);
  out_kernel<<<dim3(8, 128), 256, 0, stream>>>(Wout, bout, ws, out);
}